// Round 1
// baseline (370.597 us; speedup 1.0000x reference)
//
#include <hip/hip_runtime.h>
#include <cstdint>
#include <cstddef>

typedef __attribute__((ext_vector_type(8))) short short8;
typedef __attribute__((ext_vector_type(4))) float floatx4;

__device__ __forceinline__ unsigned short f2bf(float f) {
    union { float f; unsigned int u; } v; v.f = f;
    unsigned int r = v.u + 0x7fffu + ((v.u >> 16) & 1u);
    return (unsigned short)(r >> 16);
}
__device__ __forceinline__ float bf2f(unsigned short h) {
    union { unsigned int u; float f; } v; v.u = ((unsigned int)h) << 16;
    return v.f;
}

__device__ __forceinline__ void glds16(const void* g, void* l) {
    __builtin_amdgcn_global_load_lds(
        (const __attribute__((address_space(1))) void*)g,
        (__attribute__((address_space(3))) void*)l, 16, 0, 0);
}

// ---------------- elementwise fp32 -> bf16 ----------------
__global__ __launch_bounds__(256) void cvt_f32_bf16_kernel(
    const float* __restrict__ in, unsigned short* __restrict__ out, int n4) {
    int i = blockIdx.x * blockDim.x + threadIdx.x;
    if (i >= n4) return;
    float4 v = reinterpret_cast<const float4*>(in)[i];
    ushort4 o;
    o.x = f2bf(v.x); o.y = f2bf(v.y); o.z = f2bf(v.z); o.w = f2bf(v.w);
    reinterpret_cast<ushort4*>(out)[i] = o;
}

// ---------------- transpose fp32[R][C] -> bf16[C][R] ----------------
__global__ __launch_bounds__(256) void transpose_f32_bf16_kernel(
    const float* __restrict__ in, unsigned short* __restrict__ out, int R, int C) {
    __shared__ float tile[32][33];
    int c0 = blockIdx.x * 32, r0 = blockIdx.y * 32;
    int tx = threadIdx.x, ty = threadIdx.y;
#pragma unroll
    for (int j = 0; j < 4; ++j)
        tile[ty + j * 8][tx] = in[(size_t)(r0 + ty + j * 8) * C + c0 + tx];
    __syncthreads();
#pragma unroll
    for (int j = 0; j < 4; ++j)
        out[(size_t)(c0 + ty + j * 8) * R + r0 + tx] = f2bf(tile[tx][ty + j * 8]);
}

// ---------------- transpose bf16[R][C] -> bf16[C][R], batched ----------------
__global__ __launch_bounds__(256) void transpose_bf16_kernel(
    const unsigned short* __restrict__ in, unsigned short* __restrict__ out,
    int R, int C, long long sIn, long long sOut) {
    __shared__ unsigned short tile[32][33];
    const unsigned short* ib = in + (size_t)blockIdx.z * sIn;
    unsigned short* ob = out + (size_t)blockIdx.z * sOut;
    int c0 = blockIdx.x * 32, r0 = blockIdx.y * 32;
    int tx = threadIdx.x, ty = threadIdx.y;
#pragma unroll
    for (int j = 0; j < 4; ++j)
        tile[ty + j * 8][tx] = ib[(size_t)(r0 + ty + j * 8) * C + c0 + tx];
    __syncthreads();
#pragma unroll
    for (int j = 0; j < 4; ++j)
        ob[(size_t)(c0 + ty + j * 8) * R + r0 + tx] = tile[tx][ty + j * 8];
}

// ---------------- GEMM: C[M,N] = A[M,K] @ Bt[N,K]^T (+bias[n]) ----------------
// m97 structure: 128x128 tile, BK=32, 256 threads (4 waves, 2x2 of 64x64),
// global_load_lds width-16 staging, 16x16x32 bf16 MFMA, 4x4 tiles/wave.
template <bool BF16_OUT, bool HAS_BIAS>
__global__ __launch_bounds__(256) void gemm_bt_kernel(
    const unsigned short* __restrict__ A, const unsigned short* __restrict__ Bt,
    void* __restrict__ Cv, const float* __restrict__ bias,
    int M, int N, int K, long long sA, long long sB, long long sC) {
    __shared__ unsigned short As[128 * 32];
    __shared__ unsigned short Bs[128 * 32];

    const int tid = threadIdx.x;
    const int wave = tid >> 6, lane = tid & 63;

    const unsigned short* Ab = A + (size_t)blockIdx.z * sA + (size_t)blockIdx.y * 128 * K;
    const unsigned short* Bb = Bt + (size_t)blockIdx.z * sB + (size_t)blockIdx.x * 128 * K;

    // staging: 512 chunks of 16B per tile; chunk c -> row c>>2, col (c&3)*8.
    const int c0 = wave * 64 + lane;
    const unsigned short* gA0 = Ab + (size_t)(c0 >> 2) * K + (c0 & 3) * 8;
    const unsigned short* gA1 = Ab + (size_t)((c0 + 256) >> 2) * K + (c0 & 3) * 8;
    const unsigned short* gB0 = Bb + (size_t)(c0 >> 2) * K + (c0 & 3) * 8;
    const unsigned short* gB1 = Bb + (size_t)((c0 + 256) >> 2) * K + (c0 & 3) * 8;
    // wave-uniform LDS bases (HW scatters lane*16B)
    unsigned short* lA0 = As + wave * 512;
    unsigned short* lA1 = As + 2048 + wave * 512;
    unsigned short* lB0 = Bs + wave * 512;
    unsigned short* lB1 = Bs + 2048 + wave * 512;

    // fragment read pointers: lane holds row (lane&15), k-offset (lane>>4)*8
    const unsigned short* pa = As + (size_t)(((wave >> 1) * 64 + (lane & 15)) * 32) + (lane >> 4) * 8;
    const unsigned short* pb = Bs + (size_t)(((wave & 1) * 64 + (lane & 15)) * 32) + (lane >> 4) * 8;

    floatx4 acc[4][4];
#pragma unroll
    for (int i = 0; i < 4; ++i)
#pragma unroll
        for (int j = 0; j < 4; ++j) acc[i][j] = (floatx4){0.f, 0.f, 0.f, 0.f};

    for (int k0 = 0; k0 < K; k0 += 32) {
        glds16(gA0 + k0, lA0);
        glds16(gA1 + k0, lA1);
        glds16(gB0 + k0, lB0);
        glds16(gB1 + k0, lB1);
        __syncthreads();  // drains vmcnt -> LDS tiles valid
        short8 a[4], b[4];
#pragma unroll
        for (int mt = 0; mt < 4; ++mt) a[mt] = *(const short8*)(pa + mt * 16 * 32);
#pragma unroll
        for (int nt = 0; nt < 4; ++nt) b[nt] = *(const short8*)(pb + nt * 16 * 32);
#pragma unroll
        for (int mt = 0; mt < 4; ++mt)
#pragma unroll
            for (int nt = 0; nt < 4; ++nt)
                acc[mt][nt] = __builtin_amdgcn_mfma_f32_16x16x32_bf16(a[mt], b[nt], acc[mt][nt], 0, 0, 0);
        __syncthreads();  // compute done before next stage overwrites
    }

    // epilogue: C/D layout col=lane&15, row=(lane>>4)*4+r
    const int cm = blockIdx.y * 128 + (wave >> 1) * 64 + (lane >> 4) * 4;
    const int cn = blockIdx.x * 128 + (wave & 1) * 64 + (lane & 15);
    float* Cf = (float*)Cv + (size_t)blockIdx.z * sC;
    unsigned short* Ch = (unsigned short*)Cv + (size_t)blockIdx.z * sC;
#pragma unroll
    for (int nt = 0; nt < 4; ++nt) {
        const int col = cn + nt * 16;
        const float bv = HAS_BIAS ? bias[col] : 0.f;
#pragma unroll
        for (int mt = 0; mt < 4; ++mt) {
#pragma unroll
            for (int r = 0; r < 4; ++r) {
                const int row = cm + mt * 16 + r;
                float val = acc[mt][nt][r] + bv;
                if (BF16_OUT)
                    Ch[(size_t)row * N + col] = f2bf(val);
                else
                    Cf[(size_t)row * N + col] = val;
            }
        }
    }
}

// ---------------- in-place row softmax on bf16 [rows][2048] ----------------
__global__ __launch_bounds__(256) void softmax_kernel(unsigned short* __restrict__ S, float scale) {
    unsigned short* row = S + (size_t)blockIdx.x * 2048;
    const int t = threadIdx.x;
    ushort4 u0 = reinterpret_cast<const ushort4*>(row)[t * 2];
    ushort4 u1 = reinterpret_cast<const ushort4*>(row)[t * 2 + 1];
    float v[8];
    v[0] = bf2f(u0.x) * scale; v[1] = bf2f(u0.y) * scale;
    v[2] = bf2f(u0.z) * scale; v[3] = bf2f(u0.w) * scale;
    v[4] = bf2f(u1.x) * scale; v[5] = bf2f(u1.y) * scale;
    v[6] = bf2f(u1.z) * scale; v[7] = bf2f(u1.w) * scale;

    float lm = v[0];
#pragma unroll
    for (int j = 1; j < 8; ++j) lm = fmaxf(lm, v[j]);
#pragma unroll
    for (int o = 32; o > 0; o >>= 1) lm = fmaxf(lm, __shfl_xor(lm, o));

    __shared__ float red[8];
    const int wv = t >> 6;
    if ((t & 63) == 0) red[wv] = lm;
    __syncthreads();
    const float rm = fmaxf(fmaxf(red[0], red[1]), fmaxf(red[2], red[3]));

    float s = 0.f;
#pragma unroll
    for (int j = 0; j < 8; ++j) { v[j] = __expf(v[j] - rm); s += v[j]; }
#pragma unroll
    for (int o = 32; o > 0; o >>= 1) s += __shfl_xor(s, o);
    if ((t & 63) == 0) red[4 + wv] = s;
    __syncthreads();
    const float inv = 1.f / (red[4] + red[5] + red[6] + red[7]);

    ushort4 o0, o1;
    o0.x = f2bf(v[0] * inv); o0.y = f2bf(v[1] * inv);
    o0.z = f2bf(v[2] * inv); o0.w = f2bf(v[3] * inv);
    o1.x = f2bf(v[4] * inv); o1.y = f2bf(v[5] * inv);
    o1.z = f2bf(v[6] * inv); o1.w = f2bf(v[7] * inv);
    reinterpret_cast<ushort4*>(row)[t * 2] = o0;
    reinterpret_cast<ushort4*>(row)[t * 2 + 1] = o1;
}

extern "C" void kernel_launch(void* const* d_in, const int* in_sizes, int n_in,
                              void* d_out, int out_size, void* d_ws, size_t ws_size,
                              hipStream_t stream) {
    const float* x   = (const float*)d_in[0];
    const float* ctx = (const float*)d_in[1];
    const float* Wq  = (const float*)d_in[2];
    const float* bq  = (const float*)d_in[3];
    const float* Wk  = (const float*)d_in[4];
    const float* bk  = (const float*)d_in[5];
    const float* Wv  = (const float*)d_in[6];
    const float* bv  = (const float*)d_in[7];
    float* out = (float*)d_out;

    // B=4, SQ=SKV=2048, D=1024. Flattened M = 8192 for QKV GEMMs.
    const long long S16M = 1LL << 24;  // 16 MiB
    char* ws = (char*)d_ws;
    unsigned short* xb  = (unsigned short*)(ws + 0 * S16M);
    unsigned short* cb  = (unsigned short*)(ws + 1 * S16M);
    unsigned short* Qb  = (unsigned short*)(ws + 2 * S16M);
    unsigned short* Kb  = (unsigned short*)(ws + 3 * S16M);
    unsigned short* Vb  = (unsigned short*)(ws + 4 * S16M);
    unsigned short* Vt  = (unsigned short*)(ws + 5 * S16M);
    unsigned short* Wt0 = (unsigned short*)(ws + 6 * S16M);
    unsigned short* Wt1 = Wt0 + 1024 * 1024;
    unsigned short* Wt2 = Wt1 + 1024 * 1024;
    unsigned short* Sb  = (unsigned short*)(ws + 6 * S16M + 3LL * 2097152);
    // total ws use: 6*16M + 6M + 32M = ~134 MB

    dim3 blk256(256);
    dim3 tblk(32, 8);

    // 1. convert inputs to bf16
    cvt_f32_bf16_kernel<<<8192, blk256, 0, stream>>>(x, xb, 2097152);
    cvt_f32_bf16_kernel<<<8192, blk256, 0, stream>>>(ctx, cb, 2097152);
    // 2. transpose-convert weights: W[K=1024][N=1024] -> Wt[N][K] bf16
    transpose_f32_bf16_kernel<<<dim3(32, 32), tblk, 0, stream>>>(Wq, Wt0, 1024, 1024);
    transpose_f32_bf16_kernel<<<dim3(32, 32), tblk, 0, stream>>>(Wk, Wt1, 1024, 1024);
    transpose_f32_bf16_kernel<<<dim3(32, 32), tblk, 0, stream>>>(Wv, Wt2, 1024, 1024);
    // 3. QKV GEMMs: [8192,1024] @ [1024,1024]^T + bias -> bf16
    gemm_bt_kernel<true, true><<<dim3(8, 64, 1), blk256, 0, stream>>>(
        xb, Wt0, Qb, bq, 8192, 1024, 1024, 0, 0, 0);
    gemm_bt_kernel<true, true><<<dim3(8, 64, 1), blk256, 0, stream>>>(
        cb, Wt1, Kb, bk, 8192, 1024, 1024, 0, 0, 0);
    gemm_bt_kernel<true, true><<<dim3(8, 64, 1), blk256, 0, stream>>>(
        cb, Wt2, Vb, bv, 8192, 1024, 1024, 0, 0, 0);
    // 4. V[b][2048][1024] -> Vt[b][1024][2048]
    transpose_bf16_kernel<<<dim3(32, 64, 4), tblk, 0, stream>>>(
        Vb, Vt, 2048, 1024, 2048LL * 1024, 1024LL * 2048);
    // 5. S = Q @ K^T per batch -> bf16 [b][2048][2048]
    gemm_bt_kernel<true, false><<<dim3(16, 16, 4), blk256, 0, stream>>>(
        Qb, Kb, Sb, nullptr, 2048, 2048, 1024,
        2048LL * 1024, 2048LL * 1024, 2048LL * 2048);
    // 6. softmax rows (scale folded in): 8192 rows of 2048
    softmax_kernel<<<8192, blk256, 0, stream>>>(Sb, 0.03125f);
    // 7. out = P @ Vt^T per batch -> fp32 d_out
    gemm_bt_kernel<false, false><<<dim3(8, 16, 4), blk256, 0, stream>>>(
        Sb, Vt, out, nullptr, 2048, 1024, 2048,
        2048LL * 2048, 1024LL * 2048, 2048LL * 1024);
}

// Round 2
// 294.733 us; speedup vs baseline: 1.2574x; 1.2574x over previous
//
#include <hip/hip_runtime.h>
#include <cstdint>
#include <cstddef>

typedef __attribute__((ext_vector_type(8))) short short8;
typedef __attribute__((ext_vector_type(4))) float floatx4;

__device__ __forceinline__ unsigned short f2bf(float f) {
    union { float f; unsigned int u; } v; v.f = f;
    unsigned int r = v.u + 0x7fffu + ((v.u >> 16) & 1u);
    return (unsigned short)(r >> 16);
}
__device__ __forceinline__ float bf2f(unsigned short h) {
    union { unsigned int u; float f; } v; v.u = ((unsigned int)h) << 16;
    return v.f;
}

__device__ __forceinline__ void glds16(const void* g, void* l) {
    __builtin_amdgcn_global_load_lds(
        (const __attribute__((address_space(1))) void*)g,
        (__attribute__((address_space(3))) void*)l, 16, 0, 0);
}

// ============ shared GEMM core: 128x128 tile, BK=64, XOR-swizzled LDS ============
// LDS tile physical layout: [row][pslot*8..+7] holds logical k-slot l = pslot ^ (row&7).
// Staging chunk c (0..1023): row=c>>3, pslot=c&7 -> fetch global cols (pslot^(row&7))*8.
// Fragment read: lane wants logical slot j=(lane>>4) (+4 for k+32); row&7 == lane&7,
// so phys addr = row*128B + ((j^(lane&7)))*16B; the k+32 read is the same addr ^ 64B.
// Bank math: row*128B == 0 mod 32 banks; swizzle spreads 16 lanes over all 8 slots
// twice -> 2-way conflict (free per m136) instead of 8-way.
__device__ __forceinline__ void gemm_core(
    const unsigned short* __restrict__ Ab, int ldA,
    const unsigned short* __restrict__ Bb, int ldB,
    int K,
    unsigned short* __restrict__ As, unsigned short* __restrict__ Bs,
    floatx4 (&acc)[4][4])
{
    const int tid = threadIdx.x;
    const int wave = tid >> 6, lane = tid & 63;

    const unsigned short* gA[4];
    const unsigned short* gB[4];
#pragma unroll
    for (int i = 0; i < 4; ++i) {
        const int c = i * 256 + tid;
        const int row = c >> 3;
        const int l = (c & 7) ^ (row & 7);
        gA[i] = Ab + (size_t)row * ldA + l * 8;
        gB[i] = Bb + (size_t)row * ldB + l * 8;
    }
    const int arow = (wave >> 1) * 64 + (lane & 15);
    const int brow = (wave & 1) * 64 + (lane & 15);
    const int p0 = (lane >> 4) ^ (lane & 7);
    const unsigned short* pa0 = As + arow * 64 + p0 * 8;
    const unsigned short* pb0 = Bs + brow * 64 + p0 * 8;
    const unsigned short* pa1 = As + arow * 64 + (p0 ^ 4) * 8;
    const unsigned short* pb1 = Bs + brow * 64 + (p0 ^ 4) * 8;

    for (int k0 = 0; k0 < K; k0 += 64) {
#pragma unroll
        for (int i = 0; i < 4; ++i)
            glds16(gA[i] + k0, As + (size_t)(i * 256 + wave * 64) * 8);
#pragma unroll
        for (int i = 0; i < 4; ++i)
            glds16(gB[i] + k0, Bs + (size_t)(i * 256 + wave * 64) * 8);
        __syncthreads();
        short8 a0[4], b0[4], a1[4], b1[4];
#pragma unroll
        for (int mt = 0; mt < 4; ++mt) a0[mt] = *(const short8*)(pa0 + mt * 16 * 64);
#pragma unroll
        for (int nt = 0; nt < 4; ++nt) b0[nt] = *(const short8*)(pb0 + nt * 16 * 64);
#pragma unroll
        for (int mt = 0; mt < 4; ++mt)
#pragma unroll
            for (int nt = 0; nt < 4; ++nt)
                acc[mt][nt] = __builtin_amdgcn_mfma_f32_16x16x32_bf16(a0[mt], b0[nt], acc[mt][nt], 0, 0, 0);
#pragma unroll
        for (int mt = 0; mt < 4; ++mt) a1[mt] = *(const short8*)(pa1 + mt * 16 * 64);
#pragma unroll
        for (int nt = 0; nt < 4; ++nt) b1[nt] = *(const short8*)(pb1 + nt * 16 * 64);
#pragma unroll
        for (int mt = 0; mt < 4; ++mt)
#pragma unroll
            for (int nt = 0; nt < 4; ++nt)
                acc[mt][nt] = __builtin_amdgcn_mfma_f32_16x16x32_bf16(a1[mt], b1[nt], acc[mt][nt], 0, 0, 0);
        __syncthreads();
    }
}

// ============ fused fp32->bf16 convert of x and ctx ============
__global__ __launch_bounds__(256) void cvt2_kernel(
    const float* __restrict__ x, const float* __restrict__ ctx,
    unsigned short* __restrict__ xb, unsigned short* __restrict__ cb) {
    int i = blockIdx.x * blockDim.x + threadIdx.x;  // 0 .. 4194303 (float4 units)
    const float* in; unsigned short* out; int j;
    if (i < 2097152) { in = x; out = xb; j = i; }
    else { in = ctx; out = cb; j = i - 2097152; }
    float4 v = reinterpret_cast<const float4*>(in)[j];
    ushort4 o;
    o.x = f2bf(v.x); o.y = f2bf(v.y); o.z = f2bf(v.z); o.w = f2bf(v.w);
    reinterpret_cast<ushort4*>(out)[j] = o;
}

// ============ batched weight transpose-convert: Wq->Wt0, Wk/Wv->WtKV ============
__global__ __launch_bounds__(256) void wtr_kernel(
    const float* __restrict__ Wq, const float* __restrict__ Wk, const float* __restrict__ Wv,
    unsigned short* __restrict__ Wt0, unsigned short* __restrict__ WtKV) {
    __shared__ float tile[32][33];
    const int z = blockIdx.z;
    const float* in = (z == 0) ? Wq : (z == 1) ? Wk : Wv;
    unsigned short* out = (z == 0) ? Wt0 : (z == 1) ? WtKV : (WtKV + 1024 * 1024);
    int c0 = blockIdx.x * 32, r0 = blockIdx.y * 32;
    int tx = threadIdx.x, ty = threadIdx.y;
#pragma unroll
    for (int j = 0; j < 4; ++j)
        tile[ty + j * 8][tx] = in[(size_t)(r0 + ty + j * 8) * 1024 + c0 + tx];
    __syncthreads();
#pragma unroll
    for (int j = 0; j < 4; ++j)
        out[(size_t)(c0 + ty + j * 8) * 1024 + r0 + tx] = f2bf(tile[tx][ty + j * 8]);
}

// ============ mega QKV: 1536 virtual blocks; Q (512) + KV (1024) ============
// K written compact [8192][1024]; V written TRANSPOSED per batch [1024][2048].
__global__ __launch_bounds__(256) void qkv_kernel(
    const unsigned short* __restrict__ xb, const unsigned short* __restrict__ cb,
    const unsigned short* __restrict__ WtQ, const unsigned short* __restrict__ WtKV,
    const float* __restrict__ bq, const float* __restrict__ bk, const float* __restrict__ bv,
    unsigned short* __restrict__ Qb, unsigned short* __restrict__ Kb,
    unsigned short* __restrict__ Vt) {
    __shared__ unsigned short As[128 * 64];
    __shared__ unsigned short Bs[128 * 64];
    const int vb = blockIdx.x;
    const bool isQ = vb < 512;
    int by, bxcol;
    const unsigned short *A, *B;
    if (isQ) {
        by = vb >> 3; const int bx = vb & 7; bxcol = bx * 128;
        A = xb + (size_t)by * 128 * 1024;
        B = WtQ + (size_t)bx * 128 * 1024;
    } else {
        const int v = vb - 512;
        by = v >> 4; const int bx = v & 15; bxcol = bx * 128;
        A = cb + (size_t)by * 128 * 1024;
        B = WtKV + (size_t)bx * 128 * 1024;
    }
    floatx4 acc[4][4];
#pragma unroll
    for (int i = 0; i < 4; ++i)
#pragma unroll
        for (int j = 0; j < 4; ++j) acc[i][j] = (floatx4){0.f, 0.f, 0.f, 0.f};

    gemm_core(A, 1024, B, 1024, 1024, As, Bs, acc);

    const int wave = threadIdx.x >> 6, lane = threadIdx.x & 63;
    const int cm = by * 128 + (wave >> 1) * 64 + (lane >> 4) * 4;
    const int cn = bxcol + (wave & 1) * 64 + (lane & 15);
    if (isQ || bxcol < 1024) {
        unsigned short* O = isQ ? Qb : Kb;
        const float* bias = isQ ? bq : bk;
#pragma unroll
        for (int nt = 0; nt < 4; ++nt) {
            const int col = cn + nt * 16;
            const float bvv = bias[col];
#pragma unroll
            for (int mt = 0; mt < 4; ++mt)
#pragma unroll
                for (int r = 0; r < 4; ++r)
                    O[(size_t)(cm + mt * 16 + r) * 1024 + col] = f2bf(acc[mt][nt][r] + bvv);
        }
    } else {
        // V half -> transposed write: Vt[b][colv][q], 4 consecutive q per lane = ushort4
#pragma unroll
        for (int nt = 0; nt < 4; ++nt) {
            const int colv = cn + nt * 16 - 1024;
            const float bvv = bv[colv];
#pragma unroll
            for (int mt = 0; mt < 4; ++mt) {
                const int rowg = cm + mt * 16;
                const int b = rowg >> 11, q = rowg & 2047;
                ushort4 u;
                u.x = f2bf(acc[mt][nt][0] + bvv);
                u.y = f2bf(acc[mt][nt][1] + bvv);
                u.z = f2bf(acc[mt][nt][2] + bvv);
                u.w = f2bf(acc[mt][nt][3] + bvv);
                *reinterpret_cast<ushort4*>(Vt + (size_t)b * 2097152 + (size_t)colv * 2048 + q) = u;
            }
        }
    }
}

// ============ S = Q @ K^T (bf16 out, [b][2048][2048]) ============
__global__ __launch_bounds__(256) void qkt_kernel(
    const unsigned short* __restrict__ Qb, const unsigned short* __restrict__ Kb,
    unsigned short* __restrict__ Sb) {
    __shared__ unsigned short As[128 * 64];
    __shared__ unsigned short Bs[128 * 64];
    const int z = blockIdx.z;
    const unsigned short* A = Qb + (size_t)z * 2048 * 1024 + (size_t)blockIdx.y * 128 * 1024;
    const unsigned short* B = Kb + (size_t)z * 2048 * 1024 + (size_t)blockIdx.x * 128 * 1024;
    floatx4 acc[4][4];
#pragma unroll
    for (int i = 0; i < 4; ++i)
#pragma unroll
        for (int j = 0; j < 4; ++j) acc[i][j] = (floatx4){0.f, 0.f, 0.f, 0.f};

    gemm_core(A, 1024, B, 1024, 1024, As, Bs, acc);

    const int wave = threadIdx.x >> 6, lane = threadIdx.x & 63;
    unsigned short* C = Sb + (size_t)z * 2048 * 2048;
    const int cm = blockIdx.y * 128 + (wave >> 1) * 64 + (lane >> 4) * 4;
    const int cn = blockIdx.x * 128 + (wave & 1) * 64 + (lane & 15);
#pragma unroll
    for (int nt = 0; nt < 4; ++nt)
#pragma unroll
        for (int mt = 0; mt < 4; ++mt)
#pragma unroll
            for (int r = 0; r < 4; ++r)
                C[(size_t)(cm + mt * 16 + r) * 2048 + cn + nt * 16] = f2bf(acc[mt][nt][r]);
}

// ============ out = P @ Vt^T (fp32 out, [b][2048][1024]) ============
__global__ __launch_bounds__(256) void pv_kernel(
    const unsigned short* __restrict__ Sb, const unsigned short* __restrict__ Vt,
    float* __restrict__ out) {
    __shared__ unsigned short As[128 * 64];
    __shared__ unsigned short Bs[128 * 64];
    const int z = blockIdx.z;
    const unsigned short* A = Sb + (size_t)z * 2048 * 2048 + (size_t)blockIdx.y * 128 * 2048;
    const unsigned short* B = Vt + (size_t)z * 1024 * 2048 + (size_t)blockIdx.x * 128 * 2048;
    floatx4 acc[4][4];
#pragma unroll
    for (int i = 0; i < 4; ++i)
#pragma unroll
        for (int j = 0; j < 4; ++j) acc[i][j] = (floatx4){0.f, 0.f, 0.f, 0.f};

    gemm_core(A, 2048, B, 2048, 2048, As, Bs, acc);

    const int wave = threadIdx.x >> 6, lane = threadIdx.x & 63;
    float* C = out + (size_t)z * 2048 * 1024;
    const int cm = blockIdx.y * 128 + (wave >> 1) * 64 + (lane >> 4) * 4;
    const int cn = blockIdx.x * 128 + (wave & 1) * 64 + (lane & 15);
#pragma unroll
    for (int nt = 0; nt < 4; ++nt)
#pragma unroll
        for (int mt = 0; mt < 4; ++mt)
#pragma unroll
            for (int r = 0; r < 4; ++r)
                C[(size_t)(cm + mt * 16 + r) * 1024 + cn + nt * 16] = acc[mt][nt][r];
}

// ============ in-place row softmax on bf16 [rows][2048] ============
__global__ __launch_bounds__(256) void softmax_kernel(unsigned short* __restrict__ S, float scale) {
    unsigned short* row = S + (size_t)blockIdx.x * 2048;
    const int t = threadIdx.x;
    ushort4 u0 = reinterpret_cast<const ushort4*>(row)[t * 2];
    ushort4 u1 = reinterpret_cast<const ushort4*>(row)[t * 2 + 1];
    float v[8];
    v[0] = bf2f(u0.x) * scale; v[1] = bf2f(u0.y) * scale;
    v[2] = bf2f(u0.z) * scale; v[3] = bf2f(u0.w) * scale;
    v[4] = bf2f(u1.x) * scale; v[5] = bf2f(u1.y) * scale;
    v[6] = bf2f(u1.z) * scale; v[7] = bf2f(u1.w) * scale;

    float lm = v[0];
#pragma unroll
    for (int j = 1; j < 8; ++j) lm = fmaxf(lm, v[j]);
#pragma unroll
    for (int o = 32; o > 0; o >>= 1) lm = fmaxf(lm, __shfl_xor(lm, o));

    __shared__ float red[8];
    const int wv = t >> 6;
    if ((t & 63) == 0) red[wv] = lm;
    __syncthreads();
    const float rm = fmaxf(fmaxf(red[0], red[1]), fmaxf(red[2], red[3]));

    float s = 0.f;
#pragma unroll
    for (int j = 0; j < 8; ++j) { v[j] = __expf(v[j] - rm); s += v[j]; }
#pragma unroll
    for (int o = 32; o > 0; o >>= 1) s += __shfl_xor(s, o);
    if ((t & 63) == 0) red[4 + wv] = s;
    __syncthreads();
    const float inv = 1.f / (red[4] + red[5] + red[6] + red[7]);

    ushort4 o0, o1;
    o0.x = f2bf(v[0] * inv); o0.y = f2bf(v[1] * inv);
    o0.z = f2bf(v[2] * inv); o0.w = f2bf(v[3] * inv);
    o1.x = f2bf(v[4] * inv); o1.y = f2bf(v[5] * inv);
    o1.z = f2bf(v[6] * inv); o1.w = f2bf(v[7] * inv);
    reinterpret_cast<ushort4*>(row)[t * 2] = o0;
    reinterpret_cast<ushort4*>(row)[t * 2 + 1] = o1;
}

extern "C" void kernel_launch(void* const* d_in, const int* in_sizes, int n_in,
                              void* d_out, int out_size, void* d_ws, size_t ws_size,
                              hipStream_t stream) {
    const float* x   = (const float*)d_in[0];
    const float* ctx = (const float*)d_in[1];
    const float* Wq  = (const float*)d_in[2];
    const float* bq  = (const float*)d_in[3];
    const float* Wk  = (const float*)d_in[4];
    const float* bk  = (const float*)d_in[5];
    const float* Wv  = (const float*)d_in[6];
    const float* bv  = (const float*)d_in[7];
    float* out = (float*)d_out;

    const size_t MB = 1024 * 1024;
    char* ws = (char*)d_ws;
    unsigned short* xb   = (unsigned short*)(ws + 0 * MB);
    unsigned short* cb   = (unsigned short*)(ws + 16 * MB);
    unsigned short* Qb   = (unsigned short*)(ws + 32 * MB);
    unsigned short* Kb   = (unsigned short*)(ws + 48 * MB);
    unsigned short* Vt   = (unsigned short*)(ws + 64 * MB);
    unsigned short* Wt0  = (unsigned short*)(ws + 80 * MB);
    unsigned short* WtKV = (unsigned short*)(ws + 82 * MB);
    unsigned short* Sb   = (unsigned short*)(ws + 86 * MB);
    // total: 118 MiB

    cvt2_kernel<<<16384, 256, 0, stream>>>(x, ctx, xb, cb);
    wtr_kernel<<<dim3(32, 32, 3), dim3(32, 8), 0, stream>>>(Wq, Wk, Wv, Wt0, WtKV);
    qkv_kernel<<<1536, 256, 0, stream>>>(xb, cb, Wt0, WtKV, bq, bk, bv, Qb, Kb, Vt);
    qkt_kernel<<<dim3(16, 16, 4), 256, 0, stream>>>(Qb, Kb, Sb);
    softmax_kernel<<<8192, 256, 0, stream>>>(Sb, 0.03125f);
    pv_kernel<<<dim3(8, 16, 4), 256, 0, stream>>>(Sb, Vt, out);
}